// Round 17
// baseline (213.470 us; speedup 1.0000x reference)
//
#include <hip/hip_runtime.h>
#include <hip/hip_bf16.h>
#include <math.h>

// Shapes
#define NN 64
#define CC 64
#define TT 256
#define VV 25
#define DD 64
#define BN_EPS 1e-5f

typedef short bf16x8 __attribute__((ext_vector_type(8)));
typedef float f32x4 __attribute__((ext_vector_type(4)));

// ws layout (float offsets)
#define WS_POOLED 0            // [64][64] (fully written by k_pool)
#define WS_GATE   4096         // [64][4]
#define WS_BFUSE  4352         // [64][64]
#define WS_MASK   8448         // [25][64] f32
#define WS_ABP    10048        // u32[1600] packed bf16 (a=lo16, b=hi16)
#define WS_PART2  13248        // float2[32][1600] stage-A sums (fully written by k_fred)
#define WS_WTB    218048       // ushort[64][64][64] fused W^T bf16
#define WS_YB     349120       // ushort[64][64][6400] y bf16, layout [n][d][tv]
// per-block stat partials float2[512][1600] (6.6 MB) live in d_out's lower half

static __device__ __forceinline__ unsigned short f2bf(float x) {
    __hip_bfloat16 h = __float2bfloat16(x);
    return *(unsigned short*)&h;
}
static __device__ __forceinline__ float bf2f(unsigned short u) {
    return __uint_as_float(((unsigned)u) << 16);
}

// ---------------- K_mask: mask = tanh(FM)+1 ----------------
__global__ __launch_bounds__(256) void k_mask(const float* __restrict__ fmask, float* ws) {
    const int f = blockIdx.x * 256 + threadIdx.x;
    if (f < VV * CC) ws[WS_MASK + f] = tanhf(fmask[f]) + 1.0f;
}

// ---------------- K_pool: global average pool over (T,V) ----------------
__global__ __launch_bounds__(256) void k_pool(const float* __restrict__ x0,
                                              float* __restrict__ pooled) {
    __shared__ float red[256];
    const int bid = blockIdx.x;                // n*64 + c
    const float4* p = (const float4*)(x0 + (size_t)bid * (TT * VV));
    float s = 0.f;
    for (int k = threadIdx.x; k < (TT * VV) / 4; k += 256) {
        float4 v = p[k];
        s += v.x + v.y + v.z + v.w;
    }
    red[threadIdx.x] = s;
    __syncthreads();
    for (int off = 128; off > 0; off >>= 1) {
        if (threadIdx.x < off) red[threadIdx.x] += red[threadIdx.x + off];
        __syncthreads();
    }
    if (threadIdx.x == 0) pooled[bid] = red[0] * (1.f / (TT * VV));
}

// ---------------- K1: gate MLP + softmax, bfuse ----------------
__global__ __launch_bounds__(256) void k_gate(const float* __restrict__ fc1_w,
                                              const float* __restrict__ fc1_b,
                                              const float* __restrict__ fc2_w,
                                              const float* __restrict__ fc2_b,
                                              const float* __restrict__ lin_b,
                                              const int* __restrict__ epoch_p,
                                              float* ws) {
    const int tid = threadIdx.x;
    float* pooled = ws + WS_POOLED;
    float* gate   = ws + WS_GATE;
    float* bfuse  = ws + WS_BFUSE;

    if (tid < 64) {
        const int n = tid;
        const float* po = pooled + n * 64;
        float h[16];
        for (int q = 0; q < 16; q++) {
            float z = fc1_b[q];
            for (int j = 0; j < 64; j++) z = fmaf(fc1_w[q * 64 + j], po[j], z);
            h[q] = fmaxf(z, 0.f);
        }
        float lg[4];
        for (int k = 0; k < 4; k++) {
            float z = fc2_b[k];
            for (int q = 0; q < 16; q++) z = fmaf(fc2_w[k * 16 + q], h[q], z);
            lg[k] = z;
        }
        const int ep = epoch_p[0];
        const float tao = (ep < 60) ? (-(29.0f / 60.0f) * (float)ep + 30.0f) : 1.0f;
        float mx = -1e30f;
        for (int k = 0; k < 4; k++) { lg[k] /= tao; mx = fmaxf(mx, lg[k]); }
        float se = 0.f;
        for (int k = 0; k < 4; k++) { lg[k] = expf(lg[k] - mx); se += lg[k]; }
        const float inv = 1.f / se;
        for (int k = 0; k < 4; k++) gate[n * 4 + k] = lg[k] * inv;
    }
    __syncthreads();
    for (int f = tid; f < 4096; f += 256) {
        const int n = f >> 6, d = f & 63;
        float s = 0.f;
        for (int k = 0; k < 4; k++) s = fmaf(lin_b[k * 64 + d], gate[n * 4 + k], s);
        bfuse[f] = s;
    }
}

// ---------------- K1b: fused weight, transposed, bf16: Wtb[n][d][c] ----------------
__global__ __launch_bounds__(256) void k_wfuse(const float* __restrict__ lw, float* ws) {
    __shared__ float tile[64 * 65];
    const float* gate = ws + WS_GATE;
    unsigned short* wtb = (unsigned short*)(ws + WS_WTB);
    const int n = blockIdx.x;
    float g[4];
    for (int k = 0; k < 4; k++) g[k] = gate[n * 4 + k];
    for (int f = threadIdx.x; f < 4096; f += 256) {
        const int c = f >> 6, d = f & 63;
        float v = g[0] * lw[f] + g[1] * lw[4096 + f] + g[2] * lw[8192 + f] + g[3] * lw[12288 + f];
        tile[d * 65 + c] = v;
    }
    __syncthreads();
    for (int f = threadIdx.x; f < 4096; f += 256) {
        const int d = f >> 6, c = f & 63;
        wtb[n * 4096 + f] = f2bf(tile[d * 65 + c]);
    }
}

// ---------------- K_maing: fused gather+mask -> MFMA -> y + stat partials ----------------
// grid (8 tb, 64 n), 512 threads (8 waves: 2 row-halves x 4 d-tiles), 4 chunks of 200 rows.
// Halves barrier-coupled chunk-steps per CU (16 -> 8) at constant per-thread step work.
__global__ __launch_bounds__(512) void k_maing(const float* __restrict__ x0,
                                               const unsigned short* __restrict__ wtb,
                                               const float* __restrict__ ws,
                                               float* __restrict__ wsmut,
                                               float2* __restrict__ scr) {
    __shared__ __align__(16) char pool[64384];
    float* maskL = (float*)pool;                                      // [25][65] 6500 B
    unsigned short (*Xm)[72] = (unsigned short(*)[72])(pool + 6528);  // [224][72]: 2 halves x (100+12pad)
    const int n = blockIdx.y, tb = blockIdx.x;
    const int tid = threadIdx.x;
    const int wv = tid >> 6, lane = tid & 63;
    const int lrow = lane & 15, lgrp = lane >> 4;
    const int h = wv >> 2;                        // row-half 0/1
    const int dt = wv & 3;                        // d-tile
    const int dcol = dt * 16 + lrow;
    unsigned short* outw = (unsigned short*)(pool + 38784) + wv * 1600;  // per-wave [16][100]

    // prologue (once per block)
    for (int f = tid; f < 1600; f += 512)
        maskL[(f >> 6) * 65 + (f & 63)] = ws[WS_MASK + f];
    // zero Xm pad rows 100..111 and 212..223 (24 rows x 72)
    for (int f = tid; f < 1728; f += 512) {
        const int r = f / 72;
        const int row = (r < 12) ? (100 + r) : (200 + r);
        Xm[row][f - r * 72] = 0;
    }
    const bf16x8 w0 = *(const bf16x8*)(wtb + n * 4096 + dcol * 64 + 8 * lgrp);
    const bf16x8 w1 = *(const bf16x8*)(wtb + n * 4096 + dcol * 64 + 32 + 8 * lgrp);
    const float bfv = ws[WS_BFUSE + n * 64 + dcol];
    __syncthreads();

    float s1r[7][4], s2r[7][4];
#pragma unroll
    for (int m = 0; m < 7; m++)
#pragma unroll
        for (int r = 0; r < 4; r++) { s1r[m][r] = 0.f; s2r[m][r] = 0.f; }

    const size_t nbase = (size_t)n * (CC * TT * VV);
    unsigned short* yg = (unsigned short*)(wsmut + WS_YB) + (size_t)n * 64 * 6400;

    for (int ck = 0; ck < 4; ck++) {
        const int gcol0 = tb * 800 + ck * 200;    // ≡ 0 (mod 25)
        if (ck) __syncthreads();                  // all waves past prior chunk's Xm reads

        // stage 200-col chunk: shift-in gather + mask + f32->bf16 (6.25 float4/thread)
        for (int l4 = tid; l4 < 3200; l4 += 512) {
            const int j = l4 / 50, q = l4 - j * 50;
            const float4 xv = *(const float4*)(x0 + nbase + j * 6400 + gcol0 + q * 4);
            int jm = j; if (jm >= 50) jm -= 50; else if (jm >= 25) jm -= 25;
            const float xe[4] = {xv.x, xv.y, xv.z, xv.w};
#pragma unroll
            for (int e = 0; e < 4; e++) {
                const int r = q * 4 + e;          // 0..199
                const int trel = r / 25;          // 0..7
                const int p = r - trel * 25;
                int i = p - jm; if (i < 0) i += 25;
                // dest row: half (trel>>2), local (trel&3)*25 + i
                Xm[(trel >> 2) * 112 + (trel & 3) * 25 + i][j] = f2bf(xe[e] * maskL[i * 65 + j]);
            }
        }
        __syncthreads();

        // MFMA (wave's half+d-tile) + stats-in-registers + per-wave private outw
#pragma unroll
        for (int m = 0; m < 7; m++) {
            const bf16x8 a0 = *(const bf16x8*)&Xm[h * 112 + m * 16 + lrow][8 * lgrp];
            const bf16x8 a1 = *(const bf16x8*)&Xm[h * 112 + m * 16 + lrow][32 + 8 * lgrp];
            f32x4 a = {bfv, bfv, bfv, bfv};
            a = __builtin_amdgcn_mfma_f32_16x16x32_bf16(a0, w0, a, 0, 0, 0);
            a = __builtin_amdgcn_mfma_f32_16x16x32_bf16(a1, w1, a, 0, 0, 0);
#pragma unroll
            for (int r = 0; r < 4; r++) {
                const int row = m * 16 + 4 * lgrp + r;    // local row within half
                if (row < 100) {
                    const unsigned short us = f2bf(a[r]);
                    const float yf = bf2f(us);
                    s1r[m][r] += yf;
                    s2r[m][r] = fmaf(yf, yf, s2r[m][r]);
                    outw[lrow * 100 + row] = us;           // private per-wave region
                }
            }
        }
        // flush my wave's 16 d-rows at cols gcol0 + h*100 .. +99 (no barrier needed)
        const int colb = gcol0 + h * 100;
#pragma unroll
        for (int it = 0; it < 7; it++) {
            const int l = lane + it * 64;
            if (l < 400) {
                const int dloc = l / 25, q = l - dloc * 25;
                const uint2 u = *(const uint2*)(outw + dloc * 100 + 4 * q);
                *(uint2*)(yg + (size_t)(dt * 16 + dloc) * 6400 + colb + 4 * q) = u;
            }
        }
    }

    // epilogue (once per block): LDS reduce (aliases maskL/Xm), plain float2 partial store
    __syncthreads();
    float* s1l = (float*)pool;                  // [25][66]
    float* s2l = s1l + 1650;
    for (int f = tid; f < 3300; f += 512) s1l[f] = 0.f;
    __syncthreads();
#pragma unroll
    for (int m = 0; m < 7; m++) {
#pragma unroll
        for (int r = 0; r < 4; r++) {
            const int row = m * 16 + 4 * lgrp + r;
            if (row < 100) {
                int vv = row;                    // global row ≡ local row (mod 25)
                if (vv >= 75) vv -= 75; else if (vv >= 50) vv -= 50; else if (vv >= 25) vv -= 25;
                __hip_atomic_fetch_add(&s1l[vv * 66 + dcol], s1r[m][r],
                                       __ATOMIC_RELAXED, __HIP_MEMORY_SCOPE_WORKGROUP);
                __hip_atomic_fetch_add(&s2l[vv * 66 + dcol], s2r[m][r],
                                       __ATOMIC_RELAXED, __HIP_MEMORY_SCOPE_WORKGROUP);
            }
        }
    }
    __syncthreads();
    float2* part = scr + (size_t)(n * 8 + tb) * 1600;
    for (int f = tid; f < 1600; f += 512) {
        float2 p;
        p.x = s1l[(f >> 6) * 66 + (f & 63)];
        p.y = s2l[(f >> 6) * 66 + (f & 63)];
        part[f] = p;                            // disjoint, coalesced, no RMW
    }
}

// ---------------- K_fred: stage-A reduce 512 partials -> 32 slice sums ----------------
// grid (7 fchunk, 32 slice). Coalesced: thread = feature; 4 independent chains.
__global__ __launch_bounds__(256) void k_fred(const float2* __restrict__ scr, float* ws) {
    const int f = blockIdx.x * 256 + threadIdx.x;
    if (f >= VV * DD) return;
    const int slice = blockIdx.y;
    const float2* part = scr + (size_t)slice * 16 * 1600;
    float a0 = 0.f, a1 = 0.f, a2 = 0.f, a3 = 0.f;
    float c0 = 0.f, c1 = 0.f, c2 = 0.f, c3 = 0.f;
#pragma unroll 4
    for (int b = 0; b < 16; b += 4) {
        const float2 p0 = part[(size_t)(b + 0) * 1600 + f];
        const float2 p1 = part[(size_t)(b + 1) * 1600 + f];
        const float2 p2 = part[(size_t)(b + 2) * 1600 + f];
        const float2 p3 = part[(size_t)(b + 3) * 1600 + f];
        a0 += p0.x; c0 += p0.y;
        a1 += p1.x; c1 += p1.y;
        a2 += p2.x; c2 += p2.y;
        a3 += p3.x; c3 += p3.y;
    }
    float2 o;
    o.x = (a0 + a1) + (a2 + a3);
    o.y = (c0 + c1) + (c2 + c3);
    ((float2*)(ws + WS_PART2))[(size_t)slice * 1600 + f] = o;
}

// ---------------- K3: finalize BN -> reduce 32 slice sums, pack bf16 (scale, shift) ----------------
__global__ __launch_bounds__(256) void k_finalize(const float* __restrict__ gamma,
                                                  const float* __restrict__ beta,
                                                  float* ws) {
    const int f = blockIdx.x * 256 + threadIdx.x;   // out-feature v*64+d
    if (f >= VV * DD) return;
    const int v = f >> 6, d = f & 63;
    const int vi = (v - d + 175) % 25;              // source (unshifted) v index
    const int fin = vi * 64 + d;

    const float2* part2 = (const float2*)(ws + WS_PART2);
    float a0 = 0.f, a1 = 0.f, a2 = 0.f, a3 = 0.f;
    float c0 = 0.f, c1 = 0.f, c2 = 0.f, c3 = 0.f;
#pragma unroll 4
    for (int b = 0; b < 32; b += 4) {
        const float2 p0 = part2[(size_t)(b + 0) * 1600 + fin];
        const float2 p1 = part2[(size_t)(b + 1) * 1600 + fin];
        const float2 p2 = part2[(size_t)(b + 2) * 1600 + fin];
        const float2 p3 = part2[(size_t)(b + 3) * 1600 + fin];
        a0 += p0.x; c0 += p0.y;
        a1 += p1.x; c1 += p1.y;
        a2 += p2.x; c2 += p2.y;
        a3 += p3.x; c3 += p3.y;
    }
    const float s1 = (a0 + a1) + (a2 + a3);
    const float s2 = (c0 + c1) + (c2 + c3);

    const float mean = s1 * (1.f / (NN * TT));
    float var = s2 * (1.f / (NN * TT)) - mean * mean;
    var = fmaxf(var, 0.f);
    const float rs = rsqrtf(var + BN_EPS);
    const float a = gamma[f] * rs;
    const float b = beta[f] - mean * a;
    ((unsigned*)ws)[WS_ABP + f] = (unsigned)f2bf(a) | (((unsigned)f2bf(b)) << 16);
}

// ---------------- K_bn: streaming BN + shift-out + residual + relu ----------------
// grid (64 d, 64 n): block owns plane (n,d): out[n,d,tv] = a[vo]*y[n,d,t*25+vs]+b[vo]+x0, relu
__global__ __launch_bounds__(256) void k_bn(const float* __restrict__ x0,
                                            const float* __restrict__ ws,
                                            float* __restrict__ out) {
    __shared__ __align__(16) unsigned short ybL[6400];   // 12800 B
    __shared__ float aL[25], bL[25];
    const int d = blockIdx.x, n = blockIdx.y;
    const int tid = threadIdx.x;
    const size_t pbase = (size_t)(n * 64 + d) * 6400;
    const unsigned short* yb = (const unsigned short*)(ws + WS_YB);

    for (int l = tid; l < 800; l += 256)
        *(uint4*)&ybL[l * 8] = *(const uint4*)(yb + pbase + l * 8);
    if (tid < 25) {
        const unsigned u = ((const unsigned*)ws)[WS_ABP + tid * 64 + d];
        aL[tid] = __uint_as_float(u << 16);
        bL[tid] = __uint_as_float(u & 0xffff0000u);
    }
    __syncthreads();

    const int sh = d % 25;
    for (int l4 = tid; l4 < 1600; l4 += 256) {
        const int e0 = 4 * l4;
        const float4 xv = *(const float4*)(x0 + pbase + e0);
        int t = e0 / 25;
        int vo = e0 - 25 * t;
        float o[4];
        const float xe[4] = {xv.x, xv.y, xv.z, xv.w};
#pragma unroll
        for (int k = 0; k < 4; k++) {
            int vs = vo - sh; if (vs < 0) vs += 25;
            const float y = bf2f(ybL[t * 25 + vs]);
            o[k] = fmaxf(fmaf(aL[vo], y, bL[vo]) + xe[k], 0.f);
            vo++; if (vo >= 25) { vo = 0; t++; }
        }
        float4 ov = {o[0], o[1], o[2], o[3]};
        *(float4*)(out + pbase + e0) = ov;
    }
}

extern "C" void kernel_launch(void* const* d_in, const int* in_sizes, int n_in,
                              void* d_out, int out_size, void* d_ws, size_t ws_size,
                              hipStream_t stream) {
    const float* x0    = (const float*)d_in[0];
    const float* fc1_w = (const float*)d_in[1];
    const float* fc1_b = (const float*)d_in[2];
    const float* fc2_w = (const float*)d_in[3];
    const float* fc2_b = (const float*)d_in[4];
    const float* lw    = (const float*)d_in[5];
    const float* lb    = (const float*)d_in[6];
    const float* fmask = (const float*)d_in[7];
    const float* gamma = (const float*)d_in[8];
    const float* beta  = (const float*)d_in[9];
    const int* epoch   = (const int*)d_in[12];
    float* ws  = (float*)d_ws;
    float* out = (float*)d_out;
    float2* scr = (float2*)d_out;                    // lower 6.6 MB of d_out as stat-partial scratch
    const unsigned short* wtb = (const unsigned short*)(ws + WS_WTB);

    k_mask<<<7, 256, 0, stream>>>(fmask, ws);
    k_pool<<<NN * CC, 256, 0, stream>>>(x0, ws + WS_POOLED);
    k_gate<<<1, 256, 0, stream>>>(fc1_w, fc1_b, fc2_w, fc2_b, lb, epoch, ws);
    k_wfuse<<<NN, 256, 0, stream>>>(lw, ws);
    k_maing<<<dim3(8, 64), 512, 0, stream>>>(x0, wtb, ws, ws, scr);
    k_fred<<<dim3(7, 32), 256, 0, stream>>>(scr, ws);
    k_finalize<<<7, 256, 0, stream>>>(gamma, beta, ws);
    k_bn<<<dim3(64, 64), 256, 0, stream>>>(x0, ws, out);
}

// Round 18
// 203.490 us; speedup vs baseline: 1.0490x; 1.0490x over previous
//
#include <hip/hip_runtime.h>
#include <hip/hip_bf16.h>
#include <math.h>

// Shapes
#define NN 64
#define CC 64
#define TT 256
#define VV 25
#define DD 64
#define BN_EPS 1e-5f

typedef short bf16x8 __attribute__((ext_vector_type(8)));
typedef float f32x4 __attribute__((ext_vector_type(4)));

// ws layout (float offsets)
#define WS_POOLED 0            // [64][64] (fully written by k_pool)
#define WS_GATE   4096         // [64][4]
#define WS_BFUSE  4352         // [64][64]
#define WS_MASK   8448         // [25][64] f32
#define WS_ABP    10048        // u32[1600] packed bf16 (a=lo16, b=hi16)
#define WS_PART2  13248        // float2[32][1600] stage-A sums (fully written by k_fred)
#define WS_WTB    218048       // ushort[64][64][64] fused W^T bf16
#define WS_YB     349120       // ushort[64][64][6400] y bf16, layout [n][d][tv]
// per-block stat partials float2[1024][1600] (13.1 MB) live in d_out's lower half

static __device__ __forceinline__ unsigned short f2bf(float x) {
    __hip_bfloat16 h = __float2bfloat16(x);
    return *(unsigned short*)&h;
}
// fast round-half-up f32->bf16 (same 0.5-ulp bound as RNE; no NaN path — inputs finite)
static __device__ __forceinline__ unsigned short f2bf_fast(float x) {
    return (unsigned short)((__float_as_uint(x) + 0x8000u) >> 16);
}
static __device__ __forceinline__ float bf2f(unsigned short u) {
    return __uint_as_float(((unsigned)u) << 16);
}

// ---------------- K_pool: global average pool over (T,V) ----------------
__global__ __launch_bounds__(256) void k_pool(const float* __restrict__ x0,
                                              float* __restrict__ pooled) {
    __shared__ float red[256];
    const int bid = blockIdx.x;                // n*64 + c
    const float4* p = (const float4*)(x0 + (size_t)bid * (TT * VV));
    float4 xv[7];
#pragma unroll
    for (int it = 0; it < 7; it++) {
        const int k = threadIdx.x + it * 256;
        if (k < 1600) xv[it] = p[k];
    }
    float s = 0.f;
#pragma unroll
    for (int it = 0; it < 7; it++) {
        const int k = threadIdx.x + it * 256;
        if (k < 1600) s += xv[it].x + xv[it].y + xv[it].z + xv[it].w;
    }
    red[threadIdx.x] = s;
    __syncthreads();
    for (int off = 128; off > 0; off >>= 1) {
        if (threadIdx.x < off) red[threadIdx.x] += red[threadIdx.x + off];
        __syncthreads();
    }
    if (threadIdx.x == 0) pooled[bid] = red[0] * (1.f / (TT * VV));
}

// ---------------- K1: gate MLP + softmax, bfuse, mask (k_mask folded in) ----------------
__global__ __launch_bounds__(256) void k_gate(const float* __restrict__ fc1_w,
                                              const float* __restrict__ fc1_b,
                                              const float* __restrict__ fc2_w,
                                              const float* __restrict__ fc2_b,
                                              const float* __restrict__ lin_b,
                                              const float* __restrict__ fmask,
                                              const int* __restrict__ epoch_p,
                                              float* ws) {
    const int tid = threadIdx.x;
    float* pooled = ws + WS_POOLED;
    float* gate   = ws + WS_GATE;
    float* bfuse  = ws + WS_BFUSE;

    for (int f = tid; f < VV * CC; f += 256) ws[WS_MASK + f] = tanhf(fmask[f]) + 1.0f;

    if (tid < 64) {
        const int n = tid;
        const float* po = pooled + n * 64;
        float h[16];
        for (int q = 0; q < 16; q++) {
            float z = fc1_b[q];
            for (int j = 0; j < 64; j++) z = fmaf(fc1_w[q * 64 + j], po[j], z);
            h[q] = fmaxf(z, 0.f);
        }
        float lg[4];
        for (int k = 0; k < 4; k++) {
            float z = fc2_b[k];
            for (int q = 0; q < 16; q++) z = fmaf(fc2_w[k * 16 + q], h[q], z);
            lg[k] = z;
        }
        const int ep = epoch_p[0];
        const float tao = (ep < 60) ? (-(29.0f / 60.0f) * (float)ep + 30.0f) : 1.0f;
        float mx = -1e30f;
        for (int k = 0; k < 4; k++) { lg[k] /= tao; mx = fmaxf(mx, lg[k]); }
        float se = 0.f;
        for (int k = 0; k < 4; k++) { lg[k] = expf(lg[k] - mx); se += lg[k]; }
        const float inv = 1.f / se;
        for (int k = 0; k < 4; k++) gate[n * 4 + k] = lg[k] * inv;
    }
    __syncthreads();
    for (int f = tid; f < 4096; f += 256) {
        const int n = f >> 6, d = f & 63;
        float s = 0.f;
        for (int k = 0; k < 4; k++) s = fmaf(lin_b[k * 64 + d], gate[n * 4 + k], s);
        bfuse[f] = s;
    }
}

// ---------------- K1b: fused weight, transposed, bf16: Wtb[n][d][c] ----------------
__global__ __launch_bounds__(256) void k_wfuse(const float* __restrict__ lw, float* ws) {
    __shared__ float tile[64 * 65];
    const float* gate = ws + WS_GATE;
    unsigned short* wtb = (unsigned short*)(ws + WS_WTB);
    const int n = blockIdx.x;
    float g[4];
    for (int k = 0; k < 4; k++) g[k] = gate[n * 4 + k];
    for (int f = threadIdx.x; f < 4096; f += 256) {
        const int c = f >> 6, d = f & 63;
        float v = g[0] * lw[f] + g[1] * lw[4096 + f] + g[2] * lw[8192 + f] + g[3] * lw[12288 + f];
        tile[d * 65 + c] = v;
    }
    __syncthreads();
    for (int f = threadIdx.x; f < 4096; f += 256) {
        const int d = f >> 6, c = f & 63;
        wtb[n * 4096 + f] = f2bf(tile[d * 65 + c]);
    }
}

// ---------------- K_maing: fused gather+mask -> MFMA -> y + stat partials ----------------
// grid (16 tb, 64 n), 256 threads, 4 chunks of 100 rows. R16 structure with:
// (a) issue-all-7-loads-then-process staging (no min-waves cap -> no spill),
// (b) 2-op bf16 convert in the hot path.
__global__ __launch_bounds__(256) void k_maing(const float* __restrict__ x0,
                                               const unsigned short* __restrict__ wtb,
                                               const float* __restrict__ ws,
                                               float* __restrict__ wsmut,
                                               float2* __restrict__ scr) {
    __shared__ __align__(16) char pool[35456];
    float* maskL = (float*)pool;                                      // [25][65] 6500 B
    unsigned short (*Xm)[72] = (unsigned short(*)[72])(pool + 6528);  // [112][72] 16128 B
    const int n = blockIdx.y, tb = blockIdx.x;
    const int tid = threadIdx.x;
    const int wv = tid >> 6, lane = tid & 63;
    const int lrow = lane & 15, lgrp = lane >> 4;
    const int dcol = wv * 16 + lrow;
    unsigned short* outw = (unsigned short*)(pool + 22656) + wv * 1600;  // per-wave [16][100]

    // prologue (once per block)
    for (int f = tid; f < 1600; f += 256)
        maskL[(f >> 6) * 65 + (f & 63)] = ws[WS_MASK + f];
    for (int f = tid; f < 864; f += 256) ((unsigned short*)Xm)[7200 + f] = 0;
    const bf16x8 w0 = *(const bf16x8*)(wtb + n * 4096 + dcol * 64 + 8 * lgrp);
    const bf16x8 w1 = *(const bf16x8*)(wtb + n * 4096 + dcol * 64 + 32 + 8 * lgrp);
    const float bfv = ws[WS_BFUSE + n * 64 + dcol];
    __syncthreads();

    float s1r[7][4], s2r[7][4];
#pragma unroll
    for (int m = 0; m < 7; m++)
#pragma unroll
        for (int r = 0; r < 4; r++) { s1r[m][r] = 0.f; s2r[m][r] = 0.f; }

    const size_t nbase = (size_t)n * (CC * TT * VV);
    unsigned short* yg = (unsigned short*)(wsmut + WS_YB) + (size_t)n * 64 * 6400;

    for (int ck = 0; ck < 4; ck++) {
        const int gcol0 = tb * 400 + ck * 100;
        if (ck) __syncthreads();      // all waves past prior chunk's Xm reads

        // ---- stage: ISSUE all 7 predicated float4 loads, then process ----
        float4 xv[7];
#pragma unroll
        for (int it = 0; it < 7; it++) {
            const int l4 = tid + it * 256;
            if (l4 < 1600) {
                const int j = l4 / 25, q = l4 - j * 25;
                xv[it] = *(const float4*)(x0 + nbase + j * 6400 + gcol0 + q * 4);
            }
        }
#pragma unroll
        for (int it = 0; it < 7; it++) {
            const int l4 = tid + it * 256;
            if (l4 < 1600) {
                const int j = l4 / 25, q = l4 - j * 25;
                int jm = j; if (jm >= 50) jm -= 50; else if (jm >= 25) jm -= 25;
                const float xe[4] = {xv[it].x, xv[it].y, xv[it].z, xv[it].w};
#pragma unroll
                for (int e = 0; e < 4; e++) {
                    const int r = q * 4 + e;
                    const int trel = (r >= 75) ? 3 : (r >= 50) ? 2 : (r >= 25) ? 1 : 0;
                    const int p = r - trel * 25;
                    int i = p - jm; if (i < 0) i += 25;
                    Xm[trel * 25 + i][j] = f2bf_fast(xe[e] * maskL[i * 65 + j]);
                }
            }
        }
        __syncthreads();

        // ---- MFMA + stats-in-registers + per-wave private outw ----
#pragma unroll
        for (int m = 0; m < 7; m++) {
            const bf16x8 a0 = *(const bf16x8*)&Xm[m * 16 + lrow][8 * lgrp];
            const bf16x8 a1 = *(const bf16x8*)&Xm[m * 16 + lrow][32 + 8 * lgrp];
            f32x4 a = {bfv, bfv, bfv, bfv};
            a = __builtin_amdgcn_mfma_f32_16x16x32_bf16(a0, w0, a, 0, 0, 0);
            a = __builtin_amdgcn_mfma_f32_16x16x32_bf16(a1, w1, a, 0, 0, 0);
#pragma unroll
            for (int r = 0; r < 4; r++) {
                const int row = m * 16 + 4 * lgrp + r;
                if (row < 100) {
                    const unsigned short us = f2bf_fast(a[r]);
                    const float yf = bf2f(us);
                    s1r[m][r] += yf;
                    s2r[m][r] = fmaf(yf, yf, s2r[m][r]);
                    outw[lrow * 100 + row] = us;       // private per-wave region
                }
            }
        }
        // flush my wave's 16 d-rows (same-wave ordering; no barrier needed)
#pragma unroll
        for (int it = 0; it < 7; it++) {
            const int l = lane + it * 64;
            if (l < 400) {
                const int dloc = l / 25, q = l - dloc * 25;
                const uint2 u = *(const uint2*)(outw + dloc * 100 + 4 * q);
                *(uint2*)(yg + (size_t)(wv * 16 + dloc) * 6400 + gcol0 + 4 * q) = u;
            }
        }
    }

    // epilogue (once per block): LDS reduce (aliases maskL/Xm), plain float2 partial store
    __syncthreads();
    float* s1l = (float*)pool;                  // [25][66]
    float* s2l = s1l + 1650;
    for (int f = tid; f < 3300; f += 256) s1l[f] = 0.f;
    __syncthreads();
#pragma unroll
    for (int m = 0; m < 7; m++) {
#pragma unroll
        for (int r = 0; r < 4; r++) {
            const int row = m * 16 + 4 * lgrp + r;
            if (row < 100) {
                int vv = row;                    // global row ≡ row (mod 25): 400,100 ≡ 0
                if (vv >= 75) vv -= 75; else if (vv >= 50) vv -= 50; else if (vv >= 25) vv -= 25;
                __hip_atomic_fetch_add(&s1l[vv * 66 + dcol], s1r[m][r],
                                       __ATOMIC_RELAXED, __HIP_MEMORY_SCOPE_WORKGROUP);
                __hip_atomic_fetch_add(&s2l[vv * 66 + dcol], s2r[m][r],
                                       __ATOMIC_RELAXED, __HIP_MEMORY_SCOPE_WORKGROUP);
            }
        }
    }
    __syncthreads();
    float2* part = scr + (size_t)(n * 16 + tb) * 1600;
    for (int f = tid; f < 1600; f += 256) {
        float2 p;
        p.x = s1l[(f >> 6) * 66 + (f & 63)];
        p.y = s2l[(f >> 6) * 66 + (f & 63)];
        part[f] = p;                            // disjoint, coalesced, no RMW
    }
}

// ---------------- K_fred: stage-A reduce 1024 partials -> 32 slice sums ----------------
__global__ __launch_bounds__(256) void k_fred(const float2* __restrict__ scr, float* ws) {
    const int f = blockIdx.x * 256 + threadIdx.x;
    if (f >= VV * DD) return;
    const int slice = blockIdx.y;
    const float2* part = scr + (size_t)slice * 32 * 1600;
    float a0 = 0.f, a1 = 0.f, a2 = 0.f, a3 = 0.f;
    float c0 = 0.f, c1 = 0.f, c2 = 0.f, c3 = 0.f;
#pragma unroll 4
    for (int b = 0; b < 32; b += 4) {
        const float2 p0 = part[(size_t)(b + 0) * 1600 + f];
        const float2 p1 = part[(size_t)(b + 1) * 1600 + f];
        const float2 p2 = part[(size_t)(b + 2) * 1600 + f];
        const float2 p3 = part[(size_t)(b + 3) * 1600 + f];
        a0 += p0.x; c0 += p0.y;
        a1 += p1.x; c1 += p1.y;
        a2 += p2.x; c2 += p2.y;
        a3 += p3.x; c3 += p3.y;
    }
    float2 o;
    o.x = (a0 + a1) + (a2 + a3);
    o.y = (c0 + c1) + (c2 + c3);
    ((float2*)(ws + WS_PART2))[(size_t)slice * 1600 + f] = o;
}

// ---------------- K3: finalize BN -> reduce 32 slice sums, pack bf16 (scale, shift) ----------------
__global__ __launch_bounds__(256) void k_finalize(const float* __restrict__ gamma,
                                                  const float* __restrict__ beta,
                                                  float* ws) {
    const int f = blockIdx.x * 256 + threadIdx.x;   // out-feature v*64+d
    if (f >= VV * DD) return;
    const int v = f >> 6, d = f & 63;
    const int vi = (v - d + 175) % 25;              // source (unshifted) v index
    const int fin = vi * 64 + d;

    const float2* part2 = (const float2*)(ws + WS_PART2);
    float a0 = 0.f, a1 = 0.f, a2 = 0.f, a3 = 0.f;
    float c0 = 0.f, c1 = 0.f, c2 = 0.f, c3 = 0.f;
#pragma unroll 4
    for (int b = 0; b < 32; b += 4) {
        const float2 p0 = part2[(size_t)(b + 0) * 1600 + fin];
        const float2 p1 = part2[(size_t)(b + 1) * 1600 + fin];
        const float2 p2 = part2[(size_t)(b + 2) * 1600 + fin];
        const float2 p3 = part2[(size_t)(b + 3) * 1600 + fin];
        a0 += p0.x; c0 += p0.y;
        a1 += p1.x; c1 += p1.y;
        a2 += p2.x; c2 += p2.y;
        a3 += p3.x; c3 += p3.y;
    }
    const float s1 = (a0 + a1) + (a2 + a3);
    const float s2 = (c0 + c1) + (c2 + c3);

    const float mean = s1 * (1.f / (NN * TT));
    float var = s2 * (1.f / (NN * TT)) - mean * mean;
    var = fmaxf(var, 0.f);
    const float rs = rsqrtf(var + BN_EPS);
    const float a = gamma[f] * rs;
    const float b = beta[f] - mean * a;
    ((unsigned*)ws)[WS_ABP + f] = (unsigned)f2bf(a) | (((unsigned)f2bf(b)) << 16);
}

// ---------------- K_bn: streaming BN + shift-out + residual + relu ----------------
__global__ __launch_bounds__(256) void k_bn(const float* __restrict__ x0,
                                            const float* __restrict__ ws,
                                            float* __restrict__ out) {
    __shared__ __align__(16) unsigned short ybL[6400];   // 12800 B
    __shared__ float aL[25], bL[25];
    const int d = blockIdx.x, n = blockIdx.y;
    const int tid = threadIdx.x;
    const size_t pbase = (size_t)(n * 64 + d) * 6400;
    const unsigned short* yb = (const unsigned short*)(ws + WS_YB);

    for (int l = tid; l < 800; l += 256)
        *(uint4*)&ybL[l * 8] = *(const uint4*)(yb + pbase + l * 8);
    if (tid < 25) {
        const unsigned u = ((const unsigned*)ws)[WS_ABP + tid * 64 + d];
        aL[tid] = __uint_as_float(u << 16);
        bL[tid] = __uint_as_float(u & 0xffff0000u);
    }
    __syncthreads();

    const int sh = d % 25;
    for (int l4 = tid; l4 < 1600; l4 += 256) {
        const int e0 = 4 * l4;
        const float4 xv = *(const float4*)(x0 + pbase + e0);
        int t = e0 / 25;
        int vo = e0 - 25 * t;
        float o[4];
        const float xe[4] = {xv.x, xv.y, xv.z, xv.w};
#pragma unroll
        for (int k = 0; k < 4; k++) {
            int vs = vo - sh; if (vs < 0) vs += 25;
            const float y = bf2f(ybL[t * 25 + vs]);
            o[k] = fmaxf(fmaf(aL[vo], y, bL[vo]) + xe[k], 0.f);
            vo++; if (vo >= 25) { vo = 0; t++; }
        }
        float4 ov = {o[0], o[1], o[2], o[3]};
        *(float4*)(out + pbase + e0) = ov;
    }
}

extern "C" void kernel_launch(void* const* d_in, const int* in_sizes, int n_in,
                              void* d_out, int out_size, void* d_ws, size_t ws_size,
                              hipStream_t stream) {
    const float* x0    = (const float*)d_in[0];
    const float* fc1_w = (const float*)d_in[1];
    const float* fc1_b = (const float*)d_in[2];
    const float* fc2_w = (const float*)d_in[3];
    const float* fc2_b = (const float*)d_in[4];
    const float* lw    = (const float*)d_in[5];
    const float* lb    = (const float*)d_in[6];
    const float* fmask = (const float*)d_in[7];
    const float* gamma = (const float*)d_in[8];
    const float* beta  = (const float*)d_in[9];
    const int* epoch   = (const int*)d_in[12];
    float* ws  = (float*)d_ws;
    float* out = (float*)d_out;
    float2* scr = (float2*)d_out;                    // lower 13.1 MB of d_out as stat-partial scratch
    const unsigned short* wtb = (const unsigned short*)(ws + WS_WTB);

    k_pool<<<NN * CC, 256, 0, stream>>>(x0, ws + WS_POOLED);
    k_gate<<<1, 256, 0, stream>>>(fc1_w, fc1_b, fc2_w, fc2_b, lb, fmask, epoch, ws);
    k_wfuse<<<NN, 256, 0, stream>>>(lw, ws);
    k_maing<<<dim3(16, 64), 256, 0, stream>>>(x0, wtb, ws, ws, scr);
    k_fred<<<dim3(7, 32), 256, 0, stream>>>(scr, ws);
    k_finalize<<<7, 256, 0, stream>>>(gamma, beta, ws);
    k_bn<<<dim3(64, 64), 256, 0, stream>>>(x0, ws, out);
}